// Round 2
// baseline (1700.642 us; speedup 1.0000x reference)
//
#include <hip/hip_runtime.h>
#include <hip/hip_bf16.h>

#define NN 50000
#define EE 800000
#define EP (EE + NN)   // edges + self loops

// NOTE: harness materializes integer inputs as int32 (even though reference is
// int64) -> edge_index must be read as const int*. Reading it as long long was
// the round-1 GPU memory fault.

// ---------------- self-loop attr: deg + sum over dst ----------------
__global__ void k_loop_acc(const int* __restrict__ ei,
                           const float* __restrict__ eattr,
                           float* __restrict__ deg, float* __restrict__ lsum) {
    int e = blockIdx.x * blockDim.x + threadIdx.x;
    if (e >= EE) return;
    int d = ei[EE + e];
    atomicAdd(&deg[d], 1.0f);
    atomicAdd(&lsum[2 * d],     eattr[2 * e]);
    atomicAdd(&lsum[2 * d + 1], eattr[2 * e + 1]);
}

__global__ void k_loop_fin(float* __restrict__ deg, float* __restrict__ lattr) {
    int n = blockIdx.x * blockDim.x + threadIdx.x;
    if (n >= NN) return;
    float dg = fmaxf(deg[n], 1.0f);
    lattr[2 * n]     /= dg;
    lattr[2 * n + 1] /= dg;
}

// ---------------- tiny projection: v[c][h] = sum_d We[c, h*D+d]*a_edge[h,d] ----
__global__ void k_v(const float* __restrict__ We1, const float* __restrict__ ae1,
                    const float* __restrict__ We2, const float* __restrict__ ae2,
                    float* __restrict__ v) {
    int t = threadIdx.x;
    if (t < 8) {            // layer1: c=t>>2 in [0,2), h=t&3 -> v[c*4+h]
        int c = t >> 2, h = t & 3;
        float s = 0.f;
        for (int d = 0; d < 64; d++) s += We1[c * 256 + h * 64 + d] * ae1[h * 64 + d];
        v[c * 4 + h] = s;
    } else if (t < 10) {    // layer2: c=t-8 -> v[8+c]
        int c = t - 8;
        float s = 0.f;
        for (int d = 0; d < 128; d++) s += We2[c * 128 + d] * ae2[d];
        v[8 + c] = s;
    }
}

// ---------------- fp32 tiled GEMM: C[M,Nc] = A[M,K] @ B[K,Nc] ----------------
// 64x64 tile / block(256), 4x4 per thread, K-step 16
__global__ void gemm_tiled(const float* __restrict__ A, const float* __restrict__ B,
                           float* __restrict__ C, int M, int K, int Nc) {
    __shared__ float As[16 * 65];
    __shared__ float Bs[16 * 64];
    int tx = threadIdx.x & 15, ty = threadIdx.x >> 4;
    int row0 = blockIdx.y * 64, col0 = blockIdx.x * 64;
    float acc[4][4] = {};
    for (int k0 = 0; k0 < K; k0 += 16) {
        #pragma unroll
        for (int i = 0; i < 4; i++) {
            int idx = threadIdx.x + 256 * i;
            int r = idx >> 4, kk = idx & 15;
            int gr = row0 + r;
            As[kk * 65 + r] = (gr < M) ? A[(size_t)gr * K + k0 + kk] : 0.f;
        }
        #pragma unroll
        for (int i = 0; i < 4; i++) {
            int idx = threadIdx.x + 256 * i;
            int kk = idx >> 6, c = idx & 63;
            Bs[kk * 64 + c] = B[(size_t)(k0 + kk) * Nc + col0 + c];
        }
        __syncthreads();
        #pragma unroll
        for (int kk = 0; kk < 16; kk++) {
            float a[4], b[4];
            #pragma unroll
            for (int i = 0; i < 4; i++) a[i] = As[kk * 65 + ty + 16 * i];
            #pragma unroll
            for (int j = 0; j < 4; j++) b[j] = Bs[kk * 64 + tx + 16 * j];
            #pragma unroll
            for (int i = 0; i < 4; i++)
                #pragma unroll
                for (int j = 0; j < 4; j++) acc[i][j] += a[i] * b[j];
        }
        __syncthreads();
    }
    #pragma unroll
    for (int i = 0; i < 4; i++) {
        int gr = row0 + ty + 16 * i;
        if (gr >= M) continue;
        #pragma unroll
        for (int j = 0; j < 4; j++)
            C[(size_t)gr * Nc + col0 + tx + 16 * j] = acc[i][j];
    }
}

// ---------------- per-node attention scalars: asrc[n,h], adst[n,h] ------------
template <int H, int D>
__global__ void k_attn(const float* __restrict__ h, const float* __restrict__ a_src,
                       const float* __restrict__ a_dst, float* __restrict__ asrc,
                       float* __restrict__ adst) {
    int node = blockIdx.x * (blockDim.x >> 6) + (threadIdx.x >> 6);
    int lane = threadIdx.x & 63;
    if (node >= NN) return;
    const float* row = h + (size_t)node * (H * D);
    #pragma unroll
    for (int hh = 0; hh < H; hh++) {
        float s1 = 0.f, s2 = 0.f;
        #pragma unroll
        for (int j = 0; j < D / 64; j++) {
            float hv = row[hh * D + j * 64 + lane];
            s1 += hv * a_src[hh * D + j * 64 + lane];
            s2 += hv * a_dst[hh * D + j * 64 + lane];
        }
        #pragma unroll
        for (int off = 32; off; off >>= 1) {
            s1 += __shfl_down(s1, off);
            s2 += __shfl_down(s2, off);
        }
        if (lane == 0) {
            asrc[node * H + hh] = s1;
            adst[node * H + hh] = s2;
        }
    }
}

// ---------------- per-edge: ex = exp(leaky_relu(alpha)), denom scatter --------
template <int H>
__global__ void k_edge(const int* __restrict__ ei, const float* __restrict__ eattr,
                       const float* __restrict__ lattr, const float* __restrict__ asrc,
                       const float* __restrict__ adst, const float* __restrict__ v,
                       float* __restrict__ ex, float* __restrict__ denom) {
    int e = blockIdx.x * blockDim.x + threadIdx.x;
    if (e >= EP) return;
    int s, d;
    float a0, a1;
    if (e < EE) {
        s = ei[e];
        d = ei[EE + e];
        a0 = eattr[2 * e];
        a1 = eattr[2 * e + 1];
    } else {
        s = d = e - EE;
        a0 = lattr[2 * s];
        a1 = lattr[2 * s + 1];
    }
    #pragma unroll
    for (int h = 0; h < H; h++) {
        float al = asrc[s * H + h] + adst[d * H + h] + a0 * v[h] + a1 * v[H + h];
        al = (al > 0.f) ? al : 0.2f * al;
        float exv = __expf(al);
        ex[(size_t)e * H + h] = exv;
        atomicAdd(&denom[d * H + h], exv);
    }
}

// ---------------- message scatter: acc[dst] += ex * h[src] --------------------
template <int CH, int H>
__global__ void k_msg(const int* __restrict__ ei, const float* __restrict__ hmat,
                      const float* __restrict__ ex, float* __restrict__ acc) {
    long long gt = (long long)blockIdx.x * blockDim.x + threadIdx.x;
    int e = (int)(gt >> 6);
    int lane = (int)(gt & 63);
    if (e >= EP) return;
    int s, d;
    if (e < EE) {
        s = ei[e];
        d = ei[EE + e];
    } else {
        s = d = e - EE;
    }
    const float* hs = hmat + (size_t)s * CH;
    float* ad = acc + (size_t)d * CH;
    #pragma unroll
    for (int j = 0; j < CH / 64; j++) {
        int c = j * 64 + lane;
        int hh = c / (CH / H);
        atomicAdd(&ad[c], ex[(size_t)e * H + hh] * hs[c]);
    }
}

// ---------------- layer1 finalize: h2 = elu(acc/denom + b1) -------------------
__global__ void k_fin1(const float* __restrict__ acc, const float* __restrict__ denom,
                       const float* __restrict__ b1, float* __restrict__ h2) {
    int idx = blockIdx.x * blockDim.x + threadIdx.x;
    if (idx >= NN * 256) return;
    int n = idx >> 8, c = idx & 255;
    float val = acc[idx] / (denom[n * 4 + (c >> 6)] + 1e-16f) + b1[c];
    h2[idx] = (val > 0.f) ? val : (__expf(val) - 1.0f);
}

// ---------------- layer2 finalize: out = out/denom + b2 -----------------------
__global__ void k_fin2(float* __restrict__ out, const float* __restrict__ denom,
                       const float* __restrict__ b2) {
    int idx = blockIdx.x * blockDim.x + threadIdx.x;
    if (idx >= NN * 128) return;
    int n = idx >> 7;
    out[idx] = out[idx] / (denom[n] + 1e-16f) + b2[idx & 127];
}

extern "C" void kernel_launch(void* const* d_in, const int* in_sizes, int n_in,
                              void* d_out, int out_size, void* d_ws, size_t ws_size,
                              hipStream_t stream) {
    const float* x     = (const float*)d_in[0];
    const int*   ei    = (const int*)d_in[1];      // int32 on device (see note)
    const float* eattr = (const float*)d_in[2];
    const float* W1    = (const float*)d_in[3];
    const float* We1   = (const float*)d_in[4];
    const float* as1   = (const float*)d_in[5];
    const float* ad1   = (const float*)d_in[6];
    const float* ae1   = (const float*)d_in[7];
    const float* b1    = (const float*)d_in[8];
    const float* W2    = (const float*)d_in[9];
    const float* We2   = (const float*)d_in[10];
    const float* as2   = (const float*)d_in[11];
    const float* ad2   = (const float*)d_in[12];
    const float* ae2   = (const float*)d_in[13];
    const float* b2    = (const float*)d_in[14];
    float* out = (float*)d_out;

    float* ws = (float*)d_ws;
    // workspace layout (floats)
    float* deg    = ws;                 // N
    float* lattr  = ws + NN;            // 2N (accumulated sums -> normalized in place)
    float* asrc1  = ws + 3 * NN;        // 4N
    float* adst1  = ws + 7 * NN;        // 4N
    float* denom1 = ws + 11 * NN;       // 4N
    float* asrc2  = ws + 15 * NN;       // N
    float* adst2  = ws + 16 * NN;       // N
    float* denom2 = ws + 17 * NN;       // N
    float* vbuf   = ws + 18 * NN;       // 64 (v1[2][4] at 0, v2[2] at 8)
    float* bufA   = vbuf + 64;          // 256N : h1, then h2 (elu) in place
    float* bufB   = bufA + (size_t)256 * NN;   // 256N : out1 acc, then g2 (first 128N)
    float* exbuf  = bufB + (size_t)256 * NN;   // 4*EP : ex1, reuse first EP for ex2

    // zero accumulators
    hipMemsetAsync(ws, 0, (size_t)(18 * NN + 64) * sizeof(float), stream);
    hipMemsetAsync(bufB, 0, (size_t)256 * NN * sizeof(float), stream);
    hipMemsetAsync(out, 0, (size_t)128 * NN * sizeof(float), stream);

    // self-loop attrs
    k_loop_acc<<<(EE + 255) / 256, 256, 0, stream>>>(ei, eattr, deg, lattr);
    k_loop_fin<<<(NN + 255) / 256, 256, 0, stream>>>(deg, lattr);
    k_v<<<1, 64, 0, stream>>>(We1, ae1, We2, ae2, vbuf);

    // ---- layer 1 ----
    gemm_tiled<<<dim3(4, (NN + 63) / 64), 256, 0, stream>>>(x, W1, bufA, NN, 128, 256);
    k_attn<4, 64><<<(NN + 3) / 4, 256, 0, stream>>>(bufA, as1, ad1, asrc1, adst1);
    k_edge<4><<<(EP + 255) / 256, 256, 0, stream>>>(ei, eattr, lattr, asrc1, adst1, vbuf,
                                                    exbuf, denom1);
    k_msg<256, 4><<<(EP + 3) / 4, 256, 0, stream>>>(ei, bufA, exbuf, bufB);
    k_fin1<<<(NN * 256 + 255) / 256, 256, 0, stream>>>(bufB, denom1, b1, bufA);

    // ---- layer 2 ----
    gemm_tiled<<<dim3(2, (NN + 63) / 64), 256, 0, stream>>>(bufA, W2, bufB, NN, 256, 128);
    k_attn<1, 128><<<(NN + 3) / 4, 256, 0, stream>>>(bufB, as2, ad2, asrc2, adst2);
    k_edge<1><<<(EP + 255) / 256, 256, 0, stream>>>(ei, eattr, lattr, asrc2, adst2, vbuf + 8,
                                                    exbuf, denom2);
    k_msg<128, 1><<<(EP + 3) / 4, 256, 0, stream>>>(ei, bufB, exbuf, out);
    k_fin2<<<(NN * 128 + 255) / 256, 256, 0, stream>>>(out, denom2, b2);
}

// Round 3
// 752.323 us; speedup vs baseline: 2.2605x; 2.2605x over previous
//
#include <hip/hip_runtime.h>
#include <hip/hip_bf16.h>

#define NN 50000
#define EE 800000
#define EP (EE + NN)            // edges + self loops
#define SCAN_B 2048
#define NB ((NN + SCAN_B - 1) / SCAN_B)   // 25 scan blocks

// NOTE: harness materializes integer inputs as int32 -> edge_index is const int*.

// ---------------- degree + self-loop attr sums over dst ----------------
__global__ void k_loop_acc(const int* __restrict__ ei,
                           const float* __restrict__ eattr,
                           int* __restrict__ idg, float* __restrict__ lsum) {
    int e = blockIdx.x * blockDim.x + threadIdx.x;
    if (e >= EE) return;
    int d = ei[EE + e];
    atomicAdd(&idg[d], 1);
    atomicAdd(&lsum[2 * d],     eattr[2 * e]);
    atomicAdd(&lsum[2 * d + 1], eattr[2 * e + 1]);
}

__global__ void k_loop_fin(const int* __restrict__ idg, float* __restrict__ lattr) {
    int n = blockIdx.x * blockDim.x + threadIdx.x;
    if (n >= NN) return;
    float dg = fmaxf((float)idg[n], 1.0f);
    lattr[2 * n]     /= dg;
    lattr[2 * n + 1] /= dg;
}

// ---------------- tiny projection: v[c][h] = sum_d We[c, h*D+d]*a_edge[h,d] ----
__global__ void k_v(const float* __restrict__ We1, const float* __restrict__ ae1,
                    const float* __restrict__ We2, const float* __restrict__ ae2,
                    float* __restrict__ v) {
    int t = threadIdx.x;
    if (t < 8) {            // layer1: c=t>>2, h=t&3 -> v[c*4+h]
        int c = t >> 2, h = t & 3;
        float s = 0.f;
        for (int d = 0; d < 64; d++) s += We1[c * 256 + h * 64 + d] * ae1[h * 64 + d];
        v[c * 4 + h] = s;
    } else if (t < 10) {    // layer2: c=t-8 -> v[8+c]
        int c = t - 8;
        float s = 0.f;
        for (int d = 0; d < 128; d++) s += We2[c * 128 + d] * ae2[d];
        v[8 + c] = s;
    }
}

// ---------------- CSR build: 3-pass exclusive scan of (idg+1), then bucket ----
__global__ void k_scan1(const int* __restrict__ idg, int* __restrict__ rowptr,
                        int* __restrict__ bsum) {
    __shared__ int sh[512];
    int t = threadIdx.x;
    int base = blockIdx.x * SCAN_B + t * 4;
    int v[4]; int s = 0;
    #pragma unroll
    for (int j = 0; j < 4; j++) {
        int i = base + j;
        v[j] = (i < NN) ? (idg[i] + 1) : 0;   // +1 = self loop
        s += v[j];
    }
    sh[t] = s;
    __syncthreads();
    for (int off = 1; off < 512; off <<= 1) {
        int a = (t >= off) ? sh[t - off] : 0;
        __syncthreads();
        sh[t] += a;
        __syncthreads();
    }
    int run = sh[t] - s;       // exclusive prefix of this thread's 4
    #pragma unroll
    for (int j = 0; j < 4; j++) {
        int i = base + j;
        if (i < NN) rowptr[i] = run;
        run += v[j];
    }
    if (t == 511) bsum[blockIdx.x] = sh[511];
}

__global__ void k_scan2(const int* __restrict__ bsum, int* __restrict__ boff,
                        int* __restrict__ rowptr) {
    if (threadIdx.x == 0) {
        int acc = 0;
        for (int b = 0; b < NB; b++) { boff[b] = acc; acc += bsum[b]; }
        rowptr[NN] = acc;      // == EP
    }
}

__global__ void k_scan3(int* __restrict__ rowptr, const int* __restrict__ boff) {
    int t = threadIdx.x;
    int i = blockIdx.x * SCAN_B + t * 4;
    int off = boff[blockIdx.x];
    #pragma unroll
    for (int j = 0; j < 4; j++)
        if (i + j < NN) rowptr[i + j] += off;
}

__global__ void k_scatter(const int* __restrict__ ei, const int* __restrict__ rowptr,
                          int* __restrict__ cnt, int* __restrict__ eid_s,
                          int* __restrict__ src_s) {
    int e = blockIdx.x * blockDim.x + threadIdx.x;
    if (e >= EP) return;
    int s, d;
    if (e < EE) { s = ei[e]; d = ei[EE + e]; }
    else        { s = d = e - EE; }
    int p = rowptr[d] + atomicAdd(&cnt[d], 1);
    eid_s[p] = e;
    src_s[p] = s;
}

// ---------------- fp32 tiled GEMM: C[M,Nc] = A[M,K] @ B[K,Nc] ----------------
__global__ void gemm_tiled(const float* __restrict__ A, const float* __restrict__ B,
                           float* __restrict__ C, int M, int K, int Nc) {
    __shared__ float As[16 * 65];
    __shared__ float Bs[16 * 64];
    int tx = threadIdx.x & 15, ty = threadIdx.x >> 4;
    int row0 = blockIdx.y * 64, col0 = blockIdx.x * 64;
    float acc[4][4] = {};
    for (int k0 = 0; k0 < K; k0 += 16) {
        #pragma unroll
        for (int i = 0; i < 4; i++) {
            int idx = threadIdx.x + 256 * i;
            int r = idx >> 4, kk = idx & 15;
            int gr = row0 + r;
            As[kk * 65 + r] = (gr < M) ? A[(size_t)gr * K + k0 + kk] : 0.f;
        }
        #pragma unroll
        for (int i = 0; i < 4; i++) {
            int idx = threadIdx.x + 256 * i;
            int kk = idx >> 6, c = idx & 63;
            Bs[kk * 64 + c] = B[(size_t)(k0 + kk) * Nc + col0 + c];
        }
        __syncthreads();
        #pragma unroll
        for (int kk = 0; kk < 16; kk++) {
            float a[4], b[4];
            #pragma unroll
            for (int i = 0; i < 4; i++) a[i] = As[kk * 65 + ty + 16 * i];
            #pragma unroll
            for (int j = 0; j < 4; j++) b[j] = Bs[kk * 64 + tx + 16 * j];
            #pragma unroll
            for (int i = 0; i < 4; i++)
                #pragma unroll
                for (int j = 0; j < 4; j++) acc[i][j] += a[i] * b[j];
        }
        __syncthreads();
    }
    #pragma unroll
    for (int i = 0; i < 4; i++) {
        int gr = row0 + ty + 16 * i;
        if (gr >= M) continue;
        #pragma unroll
        for (int j = 0; j < 4; j++)
            C[(size_t)gr * Nc + col0 + tx + 16 * j] = acc[i][j];
    }
}

// ---------------- per-node attention scalars: asrc[n,h], adst[n,h] ------------
template <int H, int D>
__global__ void k_attn(const float* __restrict__ h, const float* __restrict__ a_src,
                       const float* __restrict__ a_dst, float* __restrict__ asrc,
                       float* __restrict__ adst) {
    int node = blockIdx.x * (blockDim.x >> 6) + (threadIdx.x >> 6);
    int lane = threadIdx.x & 63;
    if (node >= NN) return;
    const float* row = h + (size_t)node * (H * D);
    #pragma unroll
    for (int hh = 0; hh < H; hh++) {
        float s1 = 0.f, s2 = 0.f;
        #pragma unroll
        for (int j = 0; j < D / 64; j++) {
            float hv = row[hh * D + j * 64 + lane];
            s1 += hv * a_src[hh * D + j * 64 + lane];
            s2 += hv * a_dst[hh * D + j * 64 + lane];
        }
        #pragma unroll
        for (int off = 32; off; off >>= 1) {
            s1 += __shfl_down(s1, off);
            s2 += __shfl_down(s2, off);
        }
        if (lane == 0) {
            asrc[node * H + hh] = s1;
            adst[node * H + hh] = s2;
        }
    }
}

// ---------------- layer1 fused softmax+aggregate+bias+ELU: one wave per node --
__global__ void k_agg1(const int* __restrict__ rowptr, const int* __restrict__ eid_s,
                       const int* __restrict__ src_s, const float* __restrict__ eattr,
                       const float* __restrict__ lattr, const float* __restrict__ asrc,
                       const float* __restrict__ adst, const float* __restrict__ v,
                       const float* __restrict__ h, const float* __restrict__ b1,
                       float* __restrict__ outp) {
    int node = blockIdx.x * 4 + (threadIdx.x >> 6);
    int lane = threadIdx.x & 63;
    if (node >= NN) return;
    int beg = rowptr[node], end = rowptr[node + 1];
    int hh = lane >> 4;                 // head = (lane*4)/64
    float ad = adst[node * 4 + hh];
    float v0 = v[hh], v1 = v[4 + hh];
    float la0 = lattr[2 * node], la1 = lattr[2 * node + 1];
    float4 acc = {0.f, 0.f, 0.f, 0.f};
    float den = 0.f;
    for (int p = beg; p < end; p++) {
        int eid = eid_s[p], s = src_s[p];
        float a0, a1;
        if (eid < EE) { a0 = eattr[2 * eid]; a1 = eattr[2 * eid + 1]; }
        else          { a0 = la0;            a1 = la1; }
        float al = asrc[s * 4 + hh] + ad + a0 * v0 + a1 * v1;
        al = (al > 0.f) ? al : 0.2f * al;
        float exv = __expf(al);
        float4 hv = *(const float4*)(h + (size_t)s * 256 + lane * 4);
        acc.x += exv * hv.x; acc.y += exv * hv.y;
        acc.z += exv * hv.z; acc.w += exv * hv.w;
        den += exv;
    }
    float inv = 1.f / (den + 1e-16f);
    float4 bv = *(const float4*)(b1 + lane * 4);
    float4 o;
    o.x = acc.x * inv + bv.x; o.y = acc.y * inv + bv.y;
    o.z = acc.z * inv + bv.z; o.w = acc.w * inv + bv.w;
    o.x = (o.x > 0.f) ? o.x : __expf(o.x) - 1.f;
    o.y = (o.y > 0.f) ? o.y : __expf(o.y) - 1.f;
    o.z = (o.z > 0.f) ? o.z : __expf(o.z) - 1.f;
    o.w = (o.w > 0.f) ? o.w : __expf(o.w) - 1.f;
    *(float4*)(outp + (size_t)node * 256 + lane * 4) = o;
}

// ---------------- layer2 fused softmax+aggregate+bias ------------------------
__global__ void k_agg2(const int* __restrict__ rowptr, const int* __restrict__ eid_s,
                       const int* __restrict__ src_s, const float* __restrict__ eattr,
                       const float* __restrict__ lattr, const float* __restrict__ asrc,
                       const float* __restrict__ adst, const float* __restrict__ v,
                       const float* __restrict__ h, const float* __restrict__ b2,
                       float* __restrict__ outp) {
    int node = blockIdx.x * 4 + (threadIdx.x >> 6);
    int lane = threadIdx.x & 63;
    if (node >= NN) return;
    int beg = rowptr[node], end = rowptr[node + 1];
    float ad = adst[node];
    float v0 = v[0], v1 = v[1];
    float la0 = lattr[2 * node], la1 = lattr[2 * node + 1];
    float2 acc = {0.f, 0.f};
    float den = 0.f;
    for (int p = beg; p < end; p++) {
        int eid = eid_s[p], s = src_s[p];
        float a0, a1;
        if (eid < EE) { a0 = eattr[2 * eid]; a1 = eattr[2 * eid + 1]; }
        else          { a0 = la0;            a1 = la1; }
        float al = asrc[s] + ad + a0 * v0 + a1 * v1;
        al = (al > 0.f) ? al : 0.2f * al;
        float exv = __expf(al);
        float2 hv = *(const float2*)(h + (size_t)s * 128 + lane * 2);
        acc.x += exv * hv.x; acc.y += exv * hv.y;
        den += exv;
    }
    float inv = 1.f / (den + 1e-16f);
    float2 o;
    o.x = acc.x * inv + b2[lane * 2];
    o.y = acc.y * inv + b2[lane * 2 + 1];
    *(float2*)(outp + (size_t)node * 128 + lane * 2) = o;
}

extern "C" void kernel_launch(void* const* d_in, const int* in_sizes, int n_in,
                              void* d_out, int out_size, void* d_ws, size_t ws_size,
                              hipStream_t stream) {
    const float* x     = (const float*)d_in[0];
    const int*   ei    = (const int*)d_in[1];      // int32 on device
    const float* eattr = (const float*)d_in[2];
    const float* W1    = (const float*)d_in[3];
    const float* We1   = (const float*)d_in[4];
    const float* as1   = (const float*)d_in[5];
    const float* ad1   = (const float*)d_in[6];
    const float* ae1   = (const float*)d_in[7];
    const float* b1    = (const float*)d_in[8];
    const float* W2    = (const float*)d_in[9];
    const float* We2   = (const float*)d_in[10];
    const float* as2   = (const float*)d_in[11];
    const float* ad2   = (const float*)d_in[12];
    const float* ae2   = (const float*)d_in[13];
    const float* b2    = (const float*)d_in[14];
    float* out = (float*)d_out;

    // workspace carve (all 4-byte units; offsets kept multiples of 4 elems
    // so float4 row loads stay 16B-aligned)
    int* idg     = (int*)d_ws;                       // NN
    int* cnt     = idg + NN;                         // NN
    float* lattr = (float*)(cnt + NN);               // 2*NN  (zeroed with idg/cnt)
    int* rowptr  = (int*)(lattr + 2 * NN);           // NN+16
    int* bsum    = rowptr + NN + 16;                 // 32
    int* boff    = bsum + 32;                        // 32
    int* eid_s   = boff + 32;                        // EP
    int* src_s   = eid_s + EP;                       // EP
    float* asrc1 = (float*)(src_s + EP);             // 4*NN
    float* adst1 = asrc1 + 4 * NN;                   // 4*NN
    float* asrc2 = adst1 + 4 * NN;                   // NN
    float* adst2 = asrc2 + NN;                       // NN
    float* vbuf  = adst2 + NN;                       // 64
    float* bufA  = vbuf + 64;                        // 256*NN
    float* bufB  = bufA + (size_t)256 * NN;          // 256*NN

    // zero idg, cnt, lattr in one shot (4*NN elems)
    hipMemsetAsync(idg, 0, (size_t)4 * NN * sizeof(int), stream);

    // degree + self-loop attrs + CSR build
    k_loop_acc<<<(EE + 255) / 256, 256, 0, stream>>>(ei, eattr, idg, lattr);
    k_loop_fin<<<(NN + 255) / 256, 256, 0, stream>>>(idg, lattr);
    k_v<<<1, 64, 0, stream>>>(We1, ae1, We2, ae2, vbuf);
    k_scan1<<<NB, 512, 0, stream>>>(idg, rowptr, bsum);
    k_scan2<<<1, 64, 0, stream>>>(bsum, boff, rowptr);
    k_scan3<<<NB, 512, 0, stream>>>(rowptr, boff);
    k_scatter<<<(EP + 255) / 256, 256, 0, stream>>>(ei, rowptr, cnt, eid_s, src_s);

    // ---- layer 1 ----
    gemm_tiled<<<dim3(4, (NN + 63) / 64), 256, 0, stream>>>(x, W1, bufA, NN, 128, 256);
    k_attn<4, 64><<<(NN + 3) / 4, 256, 0, stream>>>(bufA, as1, ad1, asrc1, adst1);
    k_agg1<<<(NN + 3) / 4, 256, 0, stream>>>(rowptr, eid_s, src_s, eattr, lattr,
                                             asrc1, adst1, vbuf, bufA, b1, bufB);

    // ---- layer 2 ----
    gemm_tiled<<<dim3(2, (NN + 63) / 64), 256, 0, stream>>>(bufB, W2, bufA, NN, 256, 128);
    k_attn<1, 128><<<(NN + 3) / 4, 256, 0, stream>>>(bufA, as2, ad2, asrc2, adst2);
    k_agg2<<<(NN + 3) / 4, 256, 0, stream>>>(rowptr, eid_s, src_s, eattr, lattr,
                                             asrc2, adst2, vbuf + 8, bufA, b2, out);
}

// Round 4
// 500.335 us; speedup vs baseline: 3.3990x; 1.5036x over previous
//
#include <hip/hip_runtime.h>
#include <hip/hip_bf16.h>

#define NN 50000
#define EE 800000
#define EP (EE + NN)            // edges + self loops (self loop = slot 0 of each node)
#define SCAN_B 2048
#define NB ((NN + SCAN_B - 1) / SCAN_B)   // 25 scan blocks

// NOTE: harness materializes integer inputs as int32 -> edge_index is const int*.

typedef short bf16x8 __attribute__((ext_vector_type(8)));
typedef float f32x4  __attribute__((ext_vector_type(4)));

__device__ __forceinline__ float bf2f(unsigned short u) {
    return __uint_as_float(((unsigned)u) << 16);
}
__device__ __forceinline__ unsigned short f2bf(float f) {
    unsigned b = __float_as_uint(f);
    b += 0x7fffu + ((b >> 16) & 1u);           // RNE
    return (unsigned short)(b >> 16);
}

// ---------------- degree histogram ----------------
__global__ void k_hist(const int* __restrict__ ei, int* __restrict__ idg) {
    int e = blockIdx.x * blockDim.x + threadIdx.x;
    if (e >= EE) return;
    atomicAdd(&idg[ei[EE + e]], 1);
}

// ---------------- tiny projection: v[c][h] = sum_d We[c, h*D+d]*a_edge[h,d] ----
__global__ void k_v(const float* __restrict__ We1, const float* __restrict__ ae1,
                    const float* __restrict__ We2, const float* __restrict__ ae2,
                    float* __restrict__ v) {
    int t = threadIdx.x;
    if (t < 8) {            // layer1: c=t>>2, h=t&3 -> v[c*4+h]
        int c = t >> 2, h = t & 3;
        float s = 0.f;
        for (int d = 0; d < 64; d++) s += We1[c * 256 + h * 64 + d] * ae1[h * 64 + d];
        v[c * 4 + h] = s;
    } else if (t < 10) {    // layer2: c=t-8 -> v[8+c]
        int c = t - 8;
        float s = 0.f;
        for (int d = 0; d < 128; d++) s += We2[c * 128 + d] * ae2[d];
        v[8 + c] = s;
    }
}

// ---------------- CSR build: 3-pass exclusive scan of (idg+1), then bucket ----
__global__ void k_scan1(const int* __restrict__ idg, int* __restrict__ rowptr,
                        int* __restrict__ bsum) {
    __shared__ int sh[512];
    int t = threadIdx.x;
    int base = blockIdx.x * SCAN_B + t * 4;
    int v[4]; int s = 0;
    #pragma unroll
    for (int j = 0; j < 4; j++) {
        int i = base + j;
        v[j] = (i < NN) ? (idg[i] + 1) : 0;   // +1 = self loop slot
        s += v[j];
    }
    sh[t] = s;
    __syncthreads();
    for (int off = 1; off < 512; off <<= 1) {
        int a = (t >= off) ? sh[t - off] : 0;
        __syncthreads();
        sh[t] += a;
        __syncthreads();
    }
    int run = sh[t] - s;
    #pragma unroll
    for (int j = 0; j < 4; j++) {
        int i = base + j;
        if (i < NN) rowptr[i] = run;
        run += v[j];
    }
    if (t == 511) bsum[blockIdx.x] = sh[511];
}

__global__ void k_scan2(const int* __restrict__ bsum, int* __restrict__ boff,
                        int* __restrict__ rowptr) {
    if (threadIdx.x == 0) {
        int acc = 0;
        for (int b = 0; b < NB; b++) { boff[b] = acc; acc += bsum[b]; }
        rowptr[NN] = acc;      // == EP
    }
}

__global__ void k_scan3(int* __restrict__ rowptr, const int* __restrict__ boff) {
    int t = threadIdx.x;
    int i = blockIdx.x * SCAN_B + t * 4;
    int off = boff[blockIdx.x];
    #pragma unroll
    for (int j = 0; j < 4; j++)
        if (i + j < NN) rowptr[i + j] += off;
}

// scatter real edges into slots [rowptr[d]+1, rowptr[d+1]); embed src + attr
__global__ void k_scatter(const int* __restrict__ ei, const float* __restrict__ eattr,
                          const int* __restrict__ rowptr, int* __restrict__ cnt,
                          int* __restrict__ src_s, float2* __restrict__ attr_s) {
    int e = blockIdx.x * blockDim.x + threadIdx.x;
    if (e >= EE) return;
    int s = ei[e], d = ei[EE + e];
    int p = rowptr[d] + 1 + atomicAdd(&cnt[d], 1);
    src_s[p] = s;
    attr_s[p] = make_float2(eattr[2 * e], eattr[2 * e + 1]);
}

// fill self-loop slot 0: src = node, attr = mean of incoming attrs
__global__ void k_selfattr(const int* __restrict__ rowptr, int* __restrict__ src_s,
                           float2* __restrict__ attr_s) {
    int n = blockIdx.x * blockDim.x + threadIdx.x;
    if (n >= NN) return;
    int beg = rowptr[n], end = rowptr[n + 1];
    float s0 = 0.f, s1 = 0.f;
    for (int p = beg + 1; p < end; p++) {
        float2 a = attr_s[p];
        s0 += a.x; s1 += a.y;
    }
    float dg = fmaxf((float)(end - beg - 1), 1.0f);
    src_s[beg] = n;
    attr_s[beg] = make_float2(s0 / dg, s1 / dg);
}

// ---------------- fp32 -> bf16 cast (x), vectorized ----------------
__global__ void k_castx(const float* __restrict__ x, unsigned short* __restrict__ xb) {
    int i = blockIdx.x * blockDim.x + threadIdx.x;
    if (i >= NN * 128 / 4) return;
    float4 v = ((const float4*)x)[i];
    ushort4 o;
    o.x = f2bf(v.x); o.y = f2bf(v.y); o.z = f2bf(v.z); o.w = f2bf(v.w);
    ((ushort4*)xb)[i] = o;
}

// ---------------- W (K x N fp32) -> Wt (N x K bf16) ----------------
__global__ void k_wt(const float* __restrict__ W, unsigned short* __restrict__ Wt,
                     int K, int N) {
    int idx = blockIdx.x * blockDim.x + threadIdx.x;
    if (idx >= K * N) return;
    int k = idx / N, n = idx - k * N;
    Wt[n * K + k] = f2bf(W[idx]);
}

// ---------------- MFMA bf16 GEMM: C[M,N] = A[M,K] @ Bt[N,K]^T, C in bf16 -----
// block 256 thr = 4 waves; block tile 128 rows x 64 cols; wave = 32 rows x 64 cols
template <int K>
__global__ __launch_bounds__(256) void gemm_mfma(const unsigned short* __restrict__ A,
                                                 const unsigned short* __restrict__ Bt,
                                                 unsigned short* __restrict__ C,
                                                 int M, int N) {
    int wave = threadIdx.x >> 6, lane = threadIdx.x & 63;
    int l16 = lane & 15, quad = lane >> 4;
    int m0 = blockIdx.y * 128 + wave * 32;
    int n0 = blockIdx.x * 64;

    f32x4 acc[2][4];
    #pragma unroll
    for (int mt = 0; mt < 2; mt++)
        #pragma unroll
        for (int nt = 0; nt < 4; nt++)
            acc[mt][nt] = (f32x4){0.f, 0.f, 0.f, 0.f};

    int ar0 = min(m0 + l16, M - 1);
    int ar1 = min(m0 + 16 + l16, M - 1);
    const unsigned short* a0 = A + (size_t)ar0 * K + quad * 8;
    const unsigned short* a1 = A + (size_t)ar1 * K + quad * 8;
    const unsigned short* bp = Bt + (size_t)(n0 + l16) * K + quad * 8;

    #pragma unroll
    for (int k0 = 0; k0 < K; k0 += 32) {
        bf16x8 af0 = *(const bf16x8*)(a0 + k0);
        bf16x8 af1 = *(const bf16x8*)(a1 + k0);
        #pragma unroll
        for (int nt = 0; nt < 4; nt++) {
            bf16x8 bf = *(const bf16x8*)(bp + (size_t)nt * 16 * K + k0);
            acc[0][nt] = __builtin_amdgcn_mfma_f32_16x16x32_bf16(af0, bf, acc[0][nt], 0, 0, 0);
            acc[1][nt] = __builtin_amdgcn_mfma_f32_16x16x32_bf16(af1, bf, acc[1][nt], 0, 0, 0);
        }
    }

    // C/D layout: col = lane&15, row = quad*4 + reg  [verified mapping]
    #pragma unroll
    for (int mt = 0; mt < 2; mt++)
        #pragma unroll
        for (int reg = 0; reg < 4; reg++) {
            int row = m0 + mt * 16 + quad * 4 + reg;
            if (row < M) {
                #pragma unroll
                for (int nt = 0; nt < 4; nt++)
                    C[(size_t)row * N + n0 + nt * 16 + l16] = f2bf(acc[mt][nt][reg]);
            }
        }
}

// ---------------- per-node attention scalars from bf16 h ----------------
template <int H, int D>
__global__ void k_attn(const unsigned short* __restrict__ hb,
                       const float* __restrict__ a_src, const float* __restrict__ a_dst,
                       float* __restrict__ asrc, float* __restrict__ adst) {
    int node = blockIdx.x * (blockDim.x >> 6) + (threadIdx.x >> 6);
    int lane = threadIdx.x & 63;
    if (node >= NN) return;
    const unsigned short* row = hb + (size_t)node * (H * D);
    #pragma unroll
    for (int hh = 0; hh < H; hh++) {
        float s1 = 0.f, s2 = 0.f;
        #pragma unroll
        for (int j = 0; j < D / 64; j++) {
            float hv = bf2f(row[hh * D + j * 64 + lane]);
            s1 += hv * a_src[hh * D + j * 64 + lane];
            s2 += hv * a_dst[hh * D + j * 64 + lane];
        }
        #pragma unroll
        for (int off = 32; off; off >>= 1) {
            s1 += __shfl_down(s1, off);
            s2 += __shfl_down(s2, off);
        }
        if (lane == 0) {
            asrc[node * H + hh] = s1;
            adst[node * H + hh] = s2;
        }
    }
}

// ---------------- layer1 fused softmax+aggregate+bias+ELU (bf16 in/out) -------
__global__ void k_agg1(const int* __restrict__ rowptr, const int* __restrict__ src_s,
                       const float2* __restrict__ attr_s, const float* __restrict__ asrc,
                       const float* __restrict__ adst, const float* __restrict__ v,
                       const unsigned short* __restrict__ hb, const float* __restrict__ b1,
                       unsigned short* __restrict__ h2b) {
    int node = blockIdx.x * 4 + (threadIdx.x >> 6);
    int lane = threadIdx.x & 63;
    if (node >= NN) return;
    int beg = rowptr[node], end = rowptr[node + 1];
    int hh = lane >> 4;                 // head = (lane*4)/64
    float ad = adst[node * 4 + hh];
    float v0 = v[hh], v1 = v[4 + hh];
    float4 acc = {0.f, 0.f, 0.f, 0.f};
    float den = 0.f;
    for (int p = beg; p < end; p++) {
        int s = src_s[p];
        float2 a = attr_s[p];
        float al = asrc[s * 4 + hh] + ad + a.x * v0 + a.y * v1;
        al = (al > 0.f) ? al : 0.2f * al;
        float exv = __expf(al);
        ushort4 raw = *(const ushort4*)(hb + (size_t)s * 256 + lane * 4);
        acc.x += exv * bf2f(raw.x); acc.y += exv * bf2f(raw.y);
        acc.z += exv * bf2f(raw.z); acc.w += exv * bf2f(raw.w);
        den += exv;
    }
    float inv = 1.f / (den + 1e-16f);
    float4 bv = *(const float4*)(b1 + lane * 4);
    float ox = acc.x * inv + bv.x, oy = acc.y * inv + bv.y;
    float oz = acc.z * inv + bv.z, ow = acc.w * inv + bv.w;
    ox = (ox > 0.f) ? ox : __expf(ox) - 1.f;
    oy = (oy > 0.f) ? oy : __expf(oy) - 1.f;
    oz = (oz > 0.f) ? oz : __expf(oz) - 1.f;
    ow = (ow > 0.f) ? ow : __expf(ow) - 1.f;
    ushort4 o;
    o.x = f2bf(ox); o.y = f2bf(oy); o.z = f2bf(oz); o.w = f2bf(ow);
    *(ushort4*)(h2b + (size_t)node * 256 + lane * 4) = o;
}

// ---------------- layer2 fused softmax+aggregate+bias (bf16 in, fp32 out) -----
__global__ void k_agg2(const int* __restrict__ rowptr, const int* __restrict__ src_s,
                       const float2* __restrict__ attr_s, const float* __restrict__ asrc,
                       const float* __restrict__ adst, const float* __restrict__ v,
                       const unsigned short* __restrict__ gb, const float* __restrict__ b2,
                       float* __restrict__ outp) {
    int node = blockIdx.x * 4 + (threadIdx.x >> 6);
    int lane = threadIdx.x & 63;
    if (node >= NN) return;
    int beg = rowptr[node], end = rowptr[node + 1];
    float ad = adst[node];
    float v0 = v[0], v1 = v[1];
    float2 acc = {0.f, 0.f};
    float den = 0.f;
    for (int p = beg; p < end; p++) {
        int s = src_s[p];
        float2 a = attr_s[p];
        float al = asrc[s] + ad + a.x * v0 + a.y * v1;
        al = (al > 0.f) ? al : 0.2f * al;
        float exv = __expf(al);
        ushort2 raw = *(const ushort2*)(gb + (size_t)s * 128 + lane * 2);
        acc.x += exv * bf2f(raw.x); acc.y += exv * bf2f(raw.y);
        den += exv;
    }
    float inv = 1.f / (den + 1e-16f);
    float2 o;
    o.x = acc.x * inv + b2[lane * 2];
    o.y = acc.y * inv + b2[lane * 2 + 1];
    *(float2*)(outp + (size_t)node * 128 + lane * 2) = o;
}

extern "C" void kernel_launch(void* const* d_in, const int* in_sizes, int n_in,
                              void* d_out, int out_size, void* d_ws, size_t ws_size,
                              hipStream_t stream) {
    const float* x     = (const float*)d_in[0];
    const int*   ei    = (const int*)d_in[1];      // int32 on device
    const float* eattr = (const float*)d_in[2];
    const float* W1    = (const float*)d_in[3];
    const float* We1   = (const float*)d_in[4];
    const float* as1   = (const float*)d_in[5];
    const float* ad1   = (const float*)d_in[6];
    const float* ae1   = (const float*)d_in[7];
    const float* b1    = (const float*)d_in[8];
    const float* W2    = (const float*)d_in[9];
    const float* We2   = (const float*)d_in[10];
    const float* as2   = (const float*)d_in[11];
    const float* ad2   = (const float*)d_in[12];
    const float* ae2   = (const float*)d_in[13];
    const float* b2    = (const float*)d_in[14];
    float* out = (float*)d_out;

    // ---- workspace carve ----
    int* idg       = (int*)d_ws;                     // NN
    int* cnt       = idg + NN;                       // NN
    int* rowptr    = cnt + NN;                       // NN+16
    int* bsum      = rowptr + NN + 16;               // 32
    int* boff      = bsum + 32;                      // 32
    int* src_s     = boff + 32;                      // EP
    float2* attr_s = (float2*)(src_s + EP);          // EP float2 (8B-aligned: offset even)
    float* asrc1   = (float*)(attr_s + EP);          // 4*NN
    float* adst1   = asrc1 + 4 * NN;                 // 4*NN
    float* asrc2   = adst1 + 4 * NN;                 // NN
    float* adst2   = asrc2 + NN;                     // NN
    float* vbuf    = adst2 + NN;                     // 64
    unsigned short* ub = (unsigned short*)(((uintptr_t)(vbuf + 64) + 63) & ~(uintptr_t)63);
    unsigned short* x_bf  = ub;                      // NN*128
    unsigned short* W1t   = x_bf + (size_t)NN * 128; // 256*128
    unsigned short* W2t   = W1t + 32768;             // 128*256
    unsigned short* h1_bf = W2t + 32768;             // NN*256
    unsigned short* h2_bf = h1_bf + (size_t)NN * 256;// NN*256
    unsigned short* g2_bf = h2_bf + (size_t)NN * 256;// NN*128

    // zero idg + cnt
    hipMemsetAsync(idg, 0, (size_t)2 * NN * sizeof(int), stream);

    // CSR build with embedded (src, attr)
    k_hist<<<(EE + 255) / 256, 256, 0, stream>>>(ei, idg);
    k_v<<<1, 64, 0, stream>>>(We1, ae1, We2, ae2, vbuf);
    k_castx<<<(NN * 128 / 4 + 255) / 256, 256, 0, stream>>>(x, x_bf);
    k_wt<<<(32768 + 255) / 256, 256, 0, stream>>>(W1, W1t, 128, 256);
    k_wt<<<(32768 + 255) / 256, 256, 0, stream>>>(W2, W2t, 256, 128);
    k_scan1<<<NB, 512, 0, stream>>>(idg, rowptr, bsum);
    k_scan2<<<1, 64, 0, stream>>>(bsum, boff, rowptr);
    k_scan3<<<NB, 512, 0, stream>>>(rowptr, boff);
    k_scatter<<<(EE + 255) / 256, 256, 0, stream>>>(ei, eattr, rowptr, cnt, src_s, attr_s);
    k_selfattr<<<(NN + 255) / 256, 256, 0, stream>>>(rowptr, src_s, attr_s);

    // ---- layer 1 ----
    gemm_mfma<128><<<dim3(4, (NN + 127) / 128), 256, 0, stream>>>(x_bf, W1t, h1_bf, NN, 256);
    k_attn<4, 64><<<(NN + 3) / 4, 256, 0, stream>>>(h1_bf, as1, ad1, asrc1, adst1);
    k_agg1<<<(NN + 3) / 4, 256, 0, stream>>>(rowptr, src_s, attr_s, asrc1, adst1, vbuf,
                                             h1_bf, b1, h2_bf);

    // ---- layer 2 ----
    gemm_mfma<256><<<dim3(2, (NN + 127) / 128), 256, 0, stream>>>(h2_bf, W2t, g2_bf, NN, 128);
    k_attn<1, 128><<<(NN + 3) / 4, 256, 0, stream>>>(g2_bf, as2, ad2, asrc2, adst2);
    k_agg2<<<(NN + 3) / 4, 256, 0, stream>>>(rowptr, src_s, attr_s, asrc2, adst2, vbuf + 8,
                                             g2_bf, b2, out);
}

// Round 5
// 398.146 us; speedup vs baseline: 4.2714x; 1.2567x over previous
//
#include <hip/hip_runtime.h>
#include <hip/hip_bf16.h>

#define NN 50000
#define EE 800000
#define EP (EE + NN)            // edges + self loops (self loop = slot 0 of each node)
#define SCAN_B 2048
#define NB ((NN + SCAN_B - 1) / SCAN_B)   // 25 scan blocks

// NOTE: harness materializes integer inputs as int32 -> edge_index is const int*.

typedef short bf16x8 __attribute__((ext_vector_type(8)));
typedef float f32x4  __attribute__((ext_vector_type(4)));

__device__ __forceinline__ float bf2f(unsigned short u) {
    return __uint_as_float(((unsigned)u) << 16);
}
__device__ __forceinline__ unsigned short f2bf(float f) {
    unsigned b = __float_as_uint(f);
    b += 0x7fffu + ((b >> 16) & 1u);           // RNE
    return (unsigned short)(b >> 16);
}

// ---------------- degree histogram ----------------
__global__ void k_hist(const int* __restrict__ ei, int* __restrict__ idg) {
    int e = blockIdx.x * blockDim.x + threadIdx.x;
    if (e >= EE) return;
    atomicAdd(&idg[ei[EE + e]], 1);
}

// ---------------- tiny projection: v[c][h] = sum_d We[c, h*D+d]*a_edge[h,d] ----
__global__ void k_v(const float* __restrict__ We1, const float* __restrict__ ae1,
                    const float* __restrict__ We2, const float* __restrict__ ae2,
                    float* __restrict__ v) {
    int t = threadIdx.x;
    if (t < 8) {            // layer1: c=t>>2, h=t&3 -> v[c*4+h]
        int c = t >> 2, h = t & 3;
        float s = 0.f;
        for (int d = 0; d < 64; d++) s += We1[c * 256 + h * 64 + d] * ae1[h * 64 + d];
        v[c * 4 + h] = s;
    } else if (t < 10) {    // layer2: c=t-8 -> v[8+c]
        int c = t - 8;
        float s = 0.f;
        for (int d = 0; d < 128; d++) s += We2[c * 128 + d] * ae2[d];
        v[8 + c] = s;
    }
}

// ---------------- CSR build: 3-pass exclusive scan of (idg+1), then bucket ----
__global__ void k_scan1(const int* __restrict__ idg, int* __restrict__ rowptr,
                        int* __restrict__ bsum) {
    __shared__ int sh[512];
    int t = threadIdx.x;
    int base = blockIdx.x * SCAN_B + t * 4;
    int v[4]; int s = 0;
    #pragma unroll
    for (int j = 0; j < 4; j++) {
        int i = base + j;
        v[j] = (i < NN) ? (idg[i] + 1) : 0;   // +1 = self loop slot
        s += v[j];
    }
    sh[t] = s;
    __syncthreads();
    for (int off = 1; off < 512; off <<= 1) {
        int a = (t >= off) ? sh[t - off] : 0;
        __syncthreads();
        sh[t] += a;
        __syncthreads();
    }
    int run = sh[t] - s;
    #pragma unroll
    for (int j = 0; j < 4; j++) {
        int i = base + j;
        if (i < NN) rowptr[i] = run;
        run += v[j];
    }
    if (t == 511) bsum[blockIdx.x] = sh[511];
}

__global__ void k_scan2(const int* __restrict__ bsum, int* __restrict__ boff,
                        int* __restrict__ rowptr) {
    if (threadIdx.x == 0) {
        int acc = 0;
        for (int b = 0; b < NB; b++) { boff[b] = acc; acc += bsum[b]; }
        rowptr[NN] = acc;      // == EP
    }
}

__global__ void k_scan3(int* __restrict__ rowptr, const int* __restrict__ boff) {
    int t = threadIdx.x;
    int i = blockIdx.x * SCAN_B + t * 4;
    int off = boff[blockIdx.x];
    #pragma unroll
    for (int j = 0; j < 4; j++)
        if (i + j < NN) rowptr[i + j] += off;
}

// scatter real edges into slots [rowptr[d]+1, rowptr[d+1]); packed {src, bf16 attrs}
__global__ void k_scatter(const int* __restrict__ ei, const float* __restrict__ eattr,
                          const int* __restrict__ rowptr, int* __restrict__ cnt,
                          int2* __restrict__ slot) {
    int e = blockIdx.x * blockDim.x + threadIdx.x;
    if (e >= EE) return;
    int s = ei[e], d = ei[EE + e];
    int p = rowptr[d] + 1 + atomicAdd(&cnt[d], 1);
    unsigned a0 = f2bf(eattr[2 * e]), a1 = f2bf(eattr[2 * e + 1]);
    slot[p] = make_int2(s, (int)(a0 | (a1 << 16)));
}

// fill self-loop slot 0: src = node, attr = mean of incoming attrs
__global__ void k_selfattr(const int* __restrict__ rowptr, int2* __restrict__ slot) {
    int n = blockIdx.x * blockDim.x + threadIdx.x;
    if (n >= NN) return;
    int beg = rowptr[n], end = rowptr[n + 1];
    float s0 = 0.f, s1 = 0.f;
    for (int p = beg + 1; p < end; p++) {
        unsigned a = (unsigned)slot[p].y;
        s0 += bf2f((unsigned short)(a & 0xffff));
        s1 += bf2f((unsigned short)(a >> 16));
    }
    float dg = fmaxf((float)(end - beg - 1), 1.0f);
    unsigned b0 = f2bf(s0 / dg), b1v = f2bf(s1 / dg);
    slot[beg] = make_int2(n, (int)(b0 | (b1v << 16)));
}

// ---------------- fp32 -> bf16 cast (x), vectorized ----------------
__global__ void k_castx(const float* __restrict__ x, unsigned short* __restrict__ xb) {
    int i = blockIdx.x * blockDim.x + threadIdx.x;
    if (i >= NN * 128 / 4) return;
    float4 v = ((const float4*)x)[i];
    ushort4 o;
    o.x = f2bf(v.x); o.y = f2bf(v.y); o.z = f2bf(v.z); o.w = f2bf(v.w);
    ((ushort4*)xb)[i] = o;
}

// ---------------- W (K x N fp32) -> Wt (N x K bf16), both weights in one ------
__global__ void k_wt(const float* __restrict__ W1, unsigned short* __restrict__ W1t,
                     const float* __restrict__ W2, unsigned short* __restrict__ W2t) {
    int idx = blockIdx.x * blockDim.x + threadIdx.x;
    if (idx < 32768) {                 // W1: 128x256 -> 256x128
        int k = idx >> 8, n = idx & 255;
        W1t[n * 128 + k] = f2bf(W1[idx]);
    } else {                           // W2: 256x128 -> 128x256
        int i = idx - 32768;
        int k = i >> 7, n = i & 127;
        W2t[n * 256 + k] = f2bf(W2[i]);
    }
}

// ---------------- MFMA bf16 GEMM: C[M,N] = A[M,K] @ Bt[N,K]^T, C in bf16 -----
template <int K>
__global__ __launch_bounds__(256) void gemm_mfma(const unsigned short* __restrict__ A,
                                                 const unsigned short* __restrict__ Bt,
                                                 unsigned short* __restrict__ C,
                                                 int M, int N) {
    int wave = threadIdx.x >> 6, lane = threadIdx.x & 63;
    int l16 = lane & 15, quad = lane >> 4;
    int m0 = blockIdx.y * 128 + wave * 32;
    int n0 = blockIdx.x * 64;

    f32x4 acc[2][4];
    #pragma unroll
    for (int mt = 0; mt < 2; mt++)
        #pragma unroll
        for (int nt = 0; nt < 4; nt++)
            acc[mt][nt] = (f32x4){0.f, 0.f, 0.f, 0.f};

    int ar0 = min(m0 + l16, M - 1);
    int ar1 = min(m0 + 16 + l16, M - 1);
    const unsigned short* a0 = A + (size_t)ar0 * K + quad * 8;
    const unsigned short* a1 = A + (size_t)ar1 * K + quad * 8;
    const unsigned short* bp = Bt + (size_t)(n0 + l16) * K + quad * 8;

    #pragma unroll
    for (int k0 = 0; k0 < K; k0 += 32) {
        bf16x8 af0 = *(const bf16x8*)(a0 + k0);
        bf16x8 af1 = *(const bf16x8*)(a1 + k0);
        #pragma unroll
        for (int nt = 0; nt < 4; nt++) {
            bf16x8 bf = *(const bf16x8*)(bp + (size_t)nt * 16 * K + k0);
            acc[0][nt] = __builtin_amdgcn_mfma_f32_16x16x32_bf16(af0, bf, acc[0][nt], 0, 0, 0);
            acc[1][nt] = __builtin_amdgcn_mfma_f32_16x16x32_bf16(af1, bf, acc[1][nt], 0, 0, 0);
        }
    }

    // C/D layout: col = lane&15, row = quad*4 + reg
    #pragma unroll
    for (int mt = 0; mt < 2; mt++)
        #pragma unroll
        for (int reg = 0; reg < 4; reg++) {
            int row = m0 + mt * 16 + quad * 4 + reg;
            if (row < M) {
                #pragma unroll
                for (int nt = 0; nt < 4; nt++)
                    C[(size_t)row * N + n0 + nt * 16 + l16] = f2bf(acc[mt][nt][reg]);
            }
        }
}

// ---------------- per-node attention scalars from bf16 h ----------------
template <int H, int D>
__global__ void k_attn(const unsigned short* __restrict__ hb,
                       const float* __restrict__ a_src, const float* __restrict__ a_dst,
                       float* __restrict__ asrc, float* __restrict__ adst) {
    int node = blockIdx.x * (blockDim.x >> 6) + (threadIdx.x >> 6);
    int lane = threadIdx.x & 63;
    if (node >= NN) return;
    const unsigned short* row = hb + (size_t)node * (H * D);
    #pragma unroll
    for (int hh = 0; hh < H; hh++) {
        float s1 = 0.f, s2 = 0.f;
        #pragma unroll
        for (int j = 0; j < D / 64; j++) {
            float hv = bf2f(row[hh * D + j * 64 + lane]);
            s1 += hv * a_src[hh * D + j * 64 + lane];
            s2 += hv * a_dst[hh * D + j * 64 + lane];
        }
        #pragma unroll
        for (int off = 32; off; off >>= 1) {
            s1 += __shfl_down(s1, off);
            s2 += __shfl_down(s2, off);
        }
        if (lane == 0) {
            asrc[node * H + hh] = s1;
            adst[node * H + hh] = s2;
        }
    }
}

// ---------------- layer1 fused softmax+aggregate+bias+ELU ---------------------
// one wave / node; alpha prefetch: lane = (edge j = lane&15, head = lane>>4);
// gather: half-wave per edge, 16B (8 bf16 ch) per lane.
__global__ __launch_bounds__(256) void k_agg1(const int* __restrict__ rowptr,
                       const int2* __restrict__ slot, const float* __restrict__ asrc,
                       const float* __restrict__ adst, const float* __restrict__ v,
                       const unsigned short* __restrict__ hb, const float* __restrict__ b1,
                       unsigned short* __restrict__ h2b) {
    int node = blockIdx.x * 4 + (threadIdx.x >> 6);
    if (node >= NN) return;
    int lane = threadIdx.x & 63;
    int j    = lane & 15;        // prefetch: edge within batch
    int hp   = lane >> 4;        // prefetch: head
    int half = lane >> 5;        // gather: which edge of the pair
    int hl   = lane & 31;        // gather: channel-lane (8 ch each)
    int hh2  = hl >> 3;          // head owning this lane's channels
    int beg = rowptr[node], end = rowptr[node + 1];
    float ad_p = adst[node * 4 + hp];
    float v0 = v[hp], v1 = v[4 + hp];
    float acc[8] = {};
    float den = 0.f;
    for (int pb = beg; pb < end; pb += 16) {
        int m = min(16, end - pb);
        int sj = 0; float exv = 0.f;
        if (j < m) {
            int2 sl = slot[pb + j];
            sj = sl.x;
            unsigned au = (unsigned)sl.y;
            float a0 = bf2f((unsigned short)(au & 0xffff));
            float a1 = bf2f((unsigned short)(au >> 16));
            float al = asrc[sj * 4 + hp] + ad_p + a0 * v0 + a1 * v1;
            al = (al > 0.f) ? al : 0.2f * al;
            exv = __expf(al);
        }
        den += exv;
        for (int j2 = 0; j2 < m; j2 += 2) {
            int jj = j2 + half;
            int s   = __shfl(sj, jj);
            float w = __shfl(exv, jj + (hh2 << 4));
            if (jj < m) {
                bf16x8 raw = *(const bf16x8*)(hb + (size_t)s * 256 + hl * 8);
                #pragma unroll
                for (int k = 0; k < 8; k++)
                    acc[k] += w * bf2f((unsigned short)raw[k]);
            }
        }
    }
    #pragma unroll
    for (int k = 0; k < 8; k++)
        acc[k] += __shfl_down(acc[k], 32);
    #pragma unroll
    for (int off = 8; off; off >>= 1) den += __shfl_xor(den, off);
    float den_h = __shfl(den, hh2 << 4);
    if (lane < 32) {
        float inv = 1.f / (den_h + 1e-16f);
        short ov[8];
        #pragma unroll
        for (int k = 0; k < 8; k++) {
            float val = acc[k] * inv + b1[hl * 8 + k];
            val = (val > 0.f) ? val : __expf(val) - 1.f;
            ov[k] = (short)f2bf(val);
        }
        bf16x8 o = {ov[0], ov[1], ov[2], ov[3], ov[4], ov[5], ov[6], ov[7]};
        *(bf16x8*)(h2b + (size_t)node * 256 + hl * 8) = o;
    }
}

// ---------------- layer2 fused softmax+aggregate+bias (H=1, 128ch, fp32 out) --
// prefetch batch of 64 edges (one per lane); gather: quarter-wave per edge.
__global__ __launch_bounds__(256) void k_agg2(const int* __restrict__ rowptr,
                       const int2* __restrict__ slot, const float* __restrict__ asrc,
                       const float* __restrict__ adst, const float* __restrict__ v,
                       const unsigned short* __restrict__ gb, const float* __restrict__ b2,
                       float* __restrict__ outp) {
    int node = blockIdx.x * 4 + (threadIdx.x >> 6);
    if (node >= NN) return;
    int lane = threadIdx.x & 63;
    int q  = lane >> 4;          // gather: which edge of the quad
    int ql = lane & 15;          // gather: channel-lane (8 ch each)
    int beg = rowptr[node], end = rowptr[node + 1];
    float ad = adst[node];
    float v0 = v[0], v1 = v[1];
    float acc[8] = {};
    float den = 0.f;
    for (int pb = beg; pb < end; pb += 64) {
        int m = min(64, end - pb);
        int sj = 0; float exv = 0.f;
        if (lane < m) {
            int2 sl = slot[pb + lane];
            sj = sl.x;
            unsigned au = (unsigned)sl.y;
            float a0 = bf2f((unsigned short)(au & 0xffff));
            float a1 = bf2f((unsigned short)(au >> 16));
            float al = asrc[sj] + ad + a0 * v0 + a1 * v1;
            al = (al > 0.f) ? al : 0.2f * al;
            exv = __expf(al);
        }
        den += exv;
        for (int j2 = 0; j2 < m; j2 += 4) {
            int jj = j2 + q;
            int s   = __shfl(sj, jj);
            float w = __shfl(exv, jj);
            if (jj < m) {
                bf16x8 raw = *(const bf16x8*)(gb + (size_t)s * 128 + ql * 8);
                #pragma unroll
                for (int k = 0; k < 8; k++)
                    acc[k] += w * bf2f((unsigned short)raw[k]);
            }
        }
    }
    #pragma unroll
    for (int k = 0; k < 8; k++) {
        acc[k] += __shfl_down(acc[k], 32);
        acc[k] += __shfl_down(acc[k], 16);
    }
    #pragma unroll
    for (int off = 32; off; off >>= 1) den += __shfl_xor(den, off);
    if (lane < 16) {
        float inv = 1.f / (den + 1e-16f);
        float o[8];
        #pragma unroll
        for (int k = 0; k < 8; k++) o[k] = acc[k] * inv + b2[ql * 8 + k];
        float4 o0 = {o[0], o[1], o[2], o[3]};
        float4 o1 = {o[4], o[5], o[6], o[7]};
        *(float4*)(outp + (size_t)node * 128 + ql * 8)     = o0;
        *(float4*)(outp + (size_t)node * 128 + ql * 8 + 4) = o1;
    }
}

extern "C" void kernel_launch(void* const* d_in, const int* in_sizes, int n_in,
                              void* d_out, int out_size, void* d_ws, size_t ws_size,
                              hipStream_t stream) {
    const float* x     = (const float*)d_in[0];
    const int*   ei    = (const int*)d_in[1];      // int32 on device
    const float* eattr = (const float*)d_in[2];
    const float* W1    = (const float*)d_in[3];
    const float* We1   = (const float*)d_in[4];
    const float* as1   = (const float*)d_in[5];
    const float* ad1   = (const float*)d_in[6];
    const float* ae1   = (const float*)d_in[7];
    const float* b1    = (const float*)d_in[8];
    const float* W2    = (const float*)d_in[9];
    const float* We2   = (const float*)d_in[10];
    const float* as2   = (const float*)d_in[11];
    const float* ad2   = (const float*)d_in[12];
    const float* ae2   = (const float*)d_in[13];
    const float* b2    = (const float*)d_in[14];
    float* out = (float*)d_out;

    // ---- workspace carve ----
    int* idg    = (int*)d_ws;                      // NN
    int* cnt    = idg + NN;                        // NN
    int* rowptr = cnt + NN;                        // NN+16
    int* bsum   = rowptr + NN + 16;                // 32
    int* boff   = bsum + 32;                       // 32
    int2* slot  = (int2*)(boff + 32);              // EP (8B-aligned: 3*NN+80 even)
    float* asrc1 = (float*)(slot + EP);            // 4*NN
    float* adst1 = asrc1 + 4 * NN;                 // 4*NN
    float* asrc2 = adst1 + 4 * NN;                 // NN
    float* adst2 = asrc2 + NN;                     // NN
    float* vbuf  = adst2 + NN;                     // 64
    unsigned short* ub = (unsigned short*)(((uintptr_t)(vbuf + 64) + 63) & ~(uintptr_t)63);
    unsigned short* x_bf  = ub;                      // NN*128
    unsigned short* W1t   = x_bf + (size_t)NN * 128; // 256*128
    unsigned short* W2t   = W1t + 32768;             // 128*256
    unsigned short* h1_bf = W2t + 32768;             // NN*256
    unsigned short* h2_bf = h1_bf + (size_t)NN * 256;// NN*256
    unsigned short* g2_bf = h2_bf + (size_t)NN * 256;// NN*128

    hipMemsetAsync(idg, 0, (size_t)2 * NN * sizeof(int), stream);

    // CSR build with embedded (src, bf16 attr)
    k_hist<<<(EE + 255) / 256, 256, 0, stream>>>(ei, idg);
    k_v<<<1, 64, 0, stream>>>(We1, ae1, We2, ae2, vbuf);
    k_castx<<<(NN * 128 / 4 + 255) / 256, 256, 0, stream>>>(x, x_bf);
    k_wt<<<(65536 + 255) / 256, 256, 0, stream>>>(W1, W1t, W2, W2t);
    k_scan1<<<NB, 512, 0, stream>>>(idg, rowptr, bsum);
    k_scan2<<<1, 64, 0, stream>>>(bsum, boff, rowptr);
    k_scan3<<<NB, 512, 0, stream>>>(rowptr, boff);
    k_scatter<<<(EE + 255) / 256, 256, 0, stream>>>(ei, eattr, rowptr, cnt, slot);
    k_selfattr<<<(NN + 255) / 256, 256, 0, stream>>>(rowptr, slot);

    // ---- layer 1 ----
    gemm_mfma<128><<<dim3(4, (NN + 127) / 128), 256, 0, stream>>>(x_bf, W1t, h1_bf, NN, 256);
    k_attn<4, 64><<<(NN + 3) / 4, 256, 0, stream>>>(h1_bf, as1, ad1, asrc1, adst1);
    k_agg1<<<(NN + 3) / 4, 256, 0, stream>>>(rowptr, slot, asrc1, adst1, vbuf,
                                             h1_bf, b1, h2_bf);

    // ---- layer 2 ----
    gemm_mfma<256><<<dim3(2, (NN + 127) / 128), 256, 0, stream>>>(h2_bf, W2t, g2_bf, NN, 128);
    k_attn<1, 128><<<(NN + 3) / 4, 256, 0, stream>>>(g2_bf, as2, ad2, asrc2, adst2);
    k_agg2<<<(NN + 3) / 4, 256, 0, stream>>>(rowptr, slot, asrc2, adst2, vbuf + 8,
                                             g2_bf, b2, out);
}

// Round 6
// 353.898 us; speedup vs baseline: 4.8055x; 1.1250x over previous
//
#include <hip/hip_runtime.h>
#include <hip/hip_bf16.h>

#define NN 50000
#define EE 800000
#define EP (EE + NN)            // edges + self loops (self loop = slot 0 of each node)
#define SCAN_B 2048
#define NB ((NN + SCAN_B - 1) / SCAN_B)   // 25 scan blocks

// NOTE: harness materializes integer inputs as int32 -> edge_index is const int*.

typedef short bf16x8 __attribute__((ext_vector_type(8)));
typedef float f32x4  __attribute__((ext_vector_type(4)));

__device__ __forceinline__ float bf2f(unsigned short u) {
    return __uint_as_float(((unsigned)u) << 16);
}
__device__ __forceinline__ unsigned short f2bf(float f) {
    unsigned b = __float_as_uint(f);
    b += 0x7fffu + ((b >> 16) & 1u);           // RNE
    return (unsigned short)(b >> 16);
}

// ---------------- fused prep: v-projection + Wt casts + degree hist + x cast --
// block 0: v ; blocks [1,256]: Wt ; [257,3381]: hist ; [3382,9631]: castx
__global__ void k_prep(const float* __restrict__ We1, const float* __restrict__ ae1,
                       const float* __restrict__ We2, const float* __restrict__ ae2,
                       float* __restrict__ v,
                       const float* __restrict__ W1, unsigned short* __restrict__ W1t,
                       const float* __restrict__ W2, unsigned short* __restrict__ W2t,
                       const int* __restrict__ ei, int* __restrict__ idg,
                       const float* __restrict__ x, unsigned short* __restrict__ xb) {
    int bid = blockIdx.x, t = threadIdx.x;
    if (bid == 0) {
        if (t < 8) {            // layer1: c=t>>2, h=t&3 -> v[c*4+h]
            int c = t >> 2, h = t & 3;
            float s = 0.f;
            for (int d = 0; d < 64; d++) s += We1[c * 256 + h * 64 + d] * ae1[h * 64 + d];
            v[c * 4 + h] = s;
        } else if (t < 10) {    // layer2: c=t-8 -> v[8+c]
            int c = t - 8;
            float s = 0.f;
            for (int d = 0; d < 128; d++) s += We2[c * 128 + d] * ae2[d];
            v[8 + c] = s;
        }
    } else if (bid <= 256) {
        int idx = (bid - 1) * 256 + t;
        if (idx < 32768) {                 // W1: 128x256 -> 256x128
            int k = idx >> 8, n = idx & 255;
            W1t[n * 128 + k] = f2bf(W1[idx]);
        } else {                           // W2: 256x128 -> 128x256
            int i = idx - 32768;
            int k = i >> 7, n = i & 127;
            W2t[n * 256 + k] = f2bf(W2[i]);
        }
    } else if (bid <= 256 + 3125) {
        int e = (bid - 257) * 256 + t;
        if (e < EE) atomicAdd(&idg[ei[EE + e]], 1);
    } else {
        int i = (bid - 3382) * 256 + t;
        if (i < NN * 128 / 4) {
            float4 vv = ((const float4*)x)[i];
            ushort4 o;
            o.x = f2bf(vv.x); o.y = f2bf(vv.y); o.z = f2bf(vv.z); o.w = f2bf(vv.w);
            ((ushort4*)xb)[i] = o;
        }
    }
}

// ---------------- CSR build: 3-pass exclusive scan of (idg+1), then bucket ----
__global__ void k_scan1(const int* __restrict__ idg, int* __restrict__ rowptr,
                        int* __restrict__ bsum) {
    __shared__ int sh[512];
    int t = threadIdx.x;
    int base = blockIdx.x * SCAN_B + t * 4;
    int v[4]; int s = 0;
    #pragma unroll
    for (int j = 0; j < 4; j++) {
        int i = base + j;
        v[j] = (i < NN) ? (idg[i] + 1) : 0;   // +1 = self loop slot
        s += v[j];
    }
    sh[t] = s;
    __syncthreads();
    for (int off = 1; off < 512; off <<= 1) {
        int a = (t >= off) ? sh[t - off] : 0;
        __syncthreads();
        sh[t] += a;
        __syncthreads();
    }
    int run = sh[t] - s;
    #pragma unroll
    for (int j = 0; j < 4; j++) {
        int i = base + j;
        if (i < NN) rowptr[i] = run;
        run += v[j];
    }
    if (t == 511) bsum[blockIdx.x] = sh[511];
}

__global__ void k_scan2(const int* __restrict__ bsum, int* __restrict__ boff,
                        int* __restrict__ rowptr) {
    if (threadIdx.x == 0) {
        int acc = 0;
        for (int b = 0; b < NB; b++) { boff[b] = acc; acc += bsum[b]; }
        rowptr[NN] = acc;      // == EP
    }
}

__global__ void k_scan3(int* __restrict__ rowptr, const int* __restrict__ boff) {
    int t = threadIdx.x;
    int i = blockIdx.x * SCAN_B + t * 4;
    int off = boff[blockIdx.x];
    #pragma unroll
    for (int j = 0; j < 4; j++)
        if (i + j < NN) rowptr[i + j] += off;
}

// scatter real edges into slots [rowptr[d]+1, rowptr[d+1]); packed {src, bf16 attrs}
__global__ void k_scatter(const int* __restrict__ ei, const float* __restrict__ eattr,
                          const int* __restrict__ rowptr, int* __restrict__ cnt,
                          int2* __restrict__ slot) {
    int e = blockIdx.x * blockDim.x + threadIdx.x;
    if (e >= EE) return;
    int s = ei[e], d = ei[EE + e];
    int p = rowptr[d] + 1 + atomicAdd(&cnt[d], 1);
    unsigned a0 = f2bf(eattr[2 * e]), a1 = f2bf(eattr[2 * e + 1]);
    slot[p] = make_int2(s, (int)(a0 | (a1 << 16)));
}

// fill self-loop slot 0: src = node, attr = mean of incoming attrs
__global__ void k_selfattr(const int* __restrict__ rowptr, int2* __restrict__ slot) {
    int n = blockIdx.x * blockDim.x + threadIdx.x;
    if (n >= NN) return;
    int beg = rowptr[n], end = rowptr[n + 1];
    float s0 = 0.f, s1 = 0.f;
    for (int p = beg + 1; p < end; p++) {
        unsigned a = (unsigned)slot[p].y;
        s0 += bf2f((unsigned short)(a & 0xffff));
        s1 += bf2f((unsigned short)(a >> 16));
    }
    float dg = fmaxf((float)(end - beg - 1), 1.0f);
    unsigned b0 = f2bf(s0 / dg), b1v = f2bf(s1 / dg);
    slot[beg] = make_int2(n, (int)(b0 | (b1v << 16)));
}

// ---------------- MFMA bf16 GEMM with fused attention-scalar epilogue ---------
// C[M,N] = A[M,K] @ Bt[N,K]^T (bf16 out). Per block: 128 rows x NT*16 cols.
// A block column covers whole head(s): layer1 NT=4 (64 cols = head blockIdx.x),
// layer2 NT=8 (all 128 cols, 1 head). asrc/adst computed from fp32 acc.
template <int K, int NT, int H>
__global__ __launch_bounds__(256) void gemm_mfma(const unsigned short* __restrict__ A,
                                                 const unsigned short* __restrict__ Bt,
                                                 unsigned short* __restrict__ C,
                                                 const float* __restrict__ avs,
                                                 const float* __restrict__ avd,
                                                 float* __restrict__ asrc,
                                                 float* __restrict__ adst,
                                                 int M, int N) {
    int wave = threadIdx.x >> 6, lane = threadIdx.x & 63;
    int l16 = lane & 15, quad = lane >> 4;
    int m0 = blockIdx.y * 128 + wave * 32;
    int n0 = blockIdx.x * (NT * 16);

    f32x4 acc[2][NT];
    #pragma unroll
    for (int mt = 0; mt < 2; mt++)
        #pragma unroll
        for (int nt = 0; nt < NT; nt++)
            acc[mt][nt] = (f32x4){0.f, 0.f, 0.f, 0.f};

    int ar0 = min(m0 + l16, M - 1);
    int ar1 = min(m0 + 16 + l16, M - 1);
    const unsigned short* a0 = A + (size_t)ar0 * K + quad * 8;
    const unsigned short* a1 = A + (size_t)ar1 * K + quad * 8;
    const unsigned short* bp = Bt + (size_t)(n0 + l16) * K + quad * 8;

    #pragma unroll
    for (int k0 = 0; k0 < K; k0 += 32) {
        bf16x8 af0 = *(const bf16x8*)(a0 + k0);
        bf16x8 af1 = *(const bf16x8*)(a1 + k0);
        #pragma unroll
        for (int nt = 0; nt < NT; nt++) {
            bf16x8 bf = *(const bf16x8*)(bp + (size_t)nt * 16 * K + k0);
            acc[0][nt] = __builtin_amdgcn_mfma_f32_16x16x32_bf16(af0, bf, acc[0][nt], 0, 0, 0);
            acc[1][nt] = __builtin_amdgcn_mfma_f32_16x16x32_bf16(af1, bf, acc[1][nt], 0, 0, 0);
        }
    }

    // C store. C/D layout: col = l16, row = quad*4 + reg
    #pragma unroll
    for (int mt = 0; mt < 2; mt++)
        #pragma unroll
        for (int reg = 0; reg < 4; reg++) {
            int row = m0 + mt * 16 + quad * 4 + reg;
            if (row < M) {
                #pragma unroll
                for (int nt = 0; nt < NT; nt++)
                    C[(size_t)row * N + n0 + nt * 16 + l16] = f2bf(acc[mt][nt][reg]);
            }
        }

    // fused attn scalars: asrc/adst[row, head] from fp32 acc
    float ws[NT], wd[NT];
    #pragma unroll
    for (int nt = 0; nt < NT; nt++) {
        ws[nt] = avs[n0 + nt * 16 + l16];
        wd[nt] = avd[n0 + nt * 16 + l16];
    }
    int hh = n0 >> 6;          // head index (layer1: blockIdx.x; layer2: 0)
    #pragma unroll
    for (int mt = 0; mt < 2; mt++)
        #pragma unroll
        for (int reg = 0; reg < 4; reg++) {
            int row = m0 + mt * 16 + quad * 4 + reg;
            float s1 = 0.f, s2 = 0.f;
            #pragma unroll
            for (int nt = 0; nt < NT; nt++) {
                float c = acc[mt][nt][reg];
                s1 += c * ws[nt];
                s2 += c * wd[nt];
            }
            #pragma unroll
            for (int off = 1; off < 16; off <<= 1) {
                s1 += __shfl_xor(s1, off);
                s2 += __shfl_xor(s2, off);
            }
            if (l16 == 0 && row < M) {
                asrc[row * H + hh] = s1;
                adst[row * H + hh] = s2;
            }
        }
}

// ---------------- layer1 fused softmax+aggregate+bias+ELU ---------------------
// one wave / node; alpha prefetch: lane = (edge j = lane&15, head = lane>>4);
// gather: half-wave per edge, 16B (8 bf16 ch) per lane. No inner guard: lanes
// past the batch carry exv=0 (and sj=0 -> valid address), contribution is 0.
__global__ __launch_bounds__(256) void k_agg1(const int* __restrict__ rowptr,
                       const int2* __restrict__ slot, const float* __restrict__ asrc,
                       const float* __restrict__ adst, const float* __restrict__ v,
                       const unsigned short* __restrict__ hb, const float* __restrict__ b1,
                       unsigned short* __restrict__ h2b) {
    int node = blockIdx.x * 4 + (threadIdx.x >> 6);
    if (node >= NN) return;
    int lane = threadIdx.x & 63;
    int j    = lane & 15;        // prefetch: edge within batch
    int hp   = lane >> 4;        // prefetch: head
    int half = lane >> 5;        // gather: which edge of the pair
    int hl   = lane & 31;        // gather: channel-lane (8 ch each)
    int hh2  = hl >> 3;          // head owning this lane's channels
    int beg = rowptr[node], end = rowptr[node + 1];
    float ad_p = adst[node * 4 + hp];
    float v0 = v[hp], v1 = v[4 + hp];
    float acc[8] = {};
    float den = 0.f;
    for (int pb = beg; pb < end; pb += 16) {
        int m = min(16, end - pb);
        int sj = 0; float exv = 0.f;
        if (j < m) {
            int2 sl = slot[pb + j];
            sj = sl.x;
            unsigned au = (unsigned)sl.y;
            float a0 = bf2f((unsigned short)(au & 0xffff));
            float a1 = bf2f((unsigned short)(au >> 16));
            float al = asrc[sj * 4 + hp] + ad_p + a0 * v0 + a1 * v1;
            al = (al > 0.f) ? al : 0.2f * al;
            exv = __expf(al);
        }
        den += exv;
        #pragma unroll 2
        for (int j2 = 0; j2 < m; j2 += 2) {
            int jj = j2 + half;                      // may hit m (odd m): w=0
            int s   = __shfl(sj, jj);
            float w = __shfl(exv, jj + (hh2 << 4));
            bf16x8 raw = *(const bf16x8*)(hb + (size_t)s * 256 + hl * 8);
            #pragma unroll
            for (int k = 0; k < 8; k++)
                acc[k] += w * bf2f((unsigned short)raw[k]);
        }
    }
    #pragma unroll
    for (int k = 0; k < 8; k++)
        acc[k] += __shfl_down(acc[k], 32);
    #pragma unroll
    for (int off = 8; off; off >>= 1) den += __shfl_xor(den, off);
    float den_h = __shfl(den, hh2 << 4);
    if (lane < 32) {
        float inv = 1.f / (den_h + 1e-16f);
        short ov[8];
        #pragma unroll
        for (int k = 0; k < 8; k++) {
            float val = acc[k] * inv + b1[hl * 8 + k];
            val = (val > 0.f) ? val : __expf(val) - 1.f;
            ov[k] = (short)f2bf(val);
        }
        bf16x8 o = {ov[0], ov[1], ov[2], ov[3], ov[4], ov[5], ov[6], ov[7]};
        *(bf16x8*)(h2b + (size_t)node * 256 + hl * 8) = o;
    }
}

// ---------------- layer2 fused softmax+aggregate+bias (H=1, 128ch, fp32 out) --
__global__ __launch_bounds__(256) void k_agg2(const int* __restrict__ rowptr,
                       const int2* __restrict__ slot, const float* __restrict__ asrc,
                       const float* __restrict__ adst, const float* __restrict__ v,
                       const unsigned short* __restrict__ gb, const float* __restrict__ b2,
                       float* __restrict__ outp) {
    int node = blockIdx.x * 4 + (threadIdx.x >> 6);
    if (node >= NN) return;
    int lane = threadIdx.x & 63;
    int q  = lane >> 4;          // gather: which edge of the quad
    int ql = lane & 15;          // gather: channel-lane (8 ch each)
    int beg = rowptr[node], end = rowptr[node + 1];
    float ad = adst[node];
    float v0 = v[0], v1 = v[1];
    float acc[8] = {};
    float den = 0.f;
    for (int pb = beg; pb < end; pb += 64) {
        int m = min(64, end - pb);
        int sj = 0; float exv = 0.f;
        if (lane < m) {
            int2 sl = slot[pb + lane];
            sj = sl.x;
            unsigned au = (unsigned)sl.y;
            float a0 = bf2f((unsigned short)(au & 0xffff));
            float a1 = bf2f((unsigned short)(au >> 16));
            float al = asrc[sj] + ad + a0 * v0 + a1 * v1;
            al = (al > 0.f) ? al : 0.2f * al;
            exv = __expf(al);
        }
        den += exv;
        #pragma unroll 2
        for (int j2 = 0; j2 < m; j2 += 4) {
            int jj = j2 + q;                         // may exceed m-1: w=0
            int s   = __shfl(sj, jj);
            float w = __shfl(exv, jj);
            bf16x8 raw = *(const bf16x8*)(gb + (size_t)s * 128 + ql * 8);
            #pragma unroll
            for (int k = 0; k < 8; k++)
                acc[k] += w * bf2f((unsigned short)raw[k]);
        }
    }
    #pragma unroll
    for (int k = 0; k < 8; k++) {
        acc[k] += __shfl_down(acc[k], 32);
        acc[k] += __shfl_down(acc[k], 16);
    }
    #pragma unroll
    for (int off = 32; off; off >>= 1) den += __shfl_xor(den, off);
    if (lane < 16) {
        float inv = 1.f / (den + 1e-16f);
        float o[8];
        #pragma unroll
        for (int k = 0; k < 8; k++) o[k] = acc[k] * inv + b2[ql * 8 + k];
        float4 o0 = {o[0], o[1], o[2], o[3]};
        float4 o1 = {o[4], o[5], o[6], o[7]};
        *(float4*)(outp + (size_t)node * 128 + ql * 8)     = o0;
        *(float4*)(outp + (size_t)node * 128 + ql * 8 + 4) = o1;
    }
}

extern "C" void kernel_launch(void* const* d_in, const int* in_sizes, int n_in,
                              void* d_out, int out_size, void* d_ws, size_t ws_size,
                              hipStream_t stream) {
    const float* x     = (const float*)d_in[0];
    const int*   ei    = (const int*)d_in[1];      // int32 on device
    const float* eattr = (const float*)d_in[2];
    const float* W1    = (const float*)d_in[3];
    const float* We1   = (const float*)d_in[4];
    const float* as1   = (const float*)d_in[5];
    const float* ad1   = (const float*)d_in[6];
    const float* ae1   = (const float*)d_in[7];
    const float* b1    = (const float*)d_in[8];
    const float* W2    = (const float*)d_in[9];
    const float* We2   = (const float*)d_in[10];
    const float* as2   = (const float*)d_in[11];
    const float* ad2   = (const float*)d_in[12];
    const float* ae2   = (const float*)d_in[13];
    const float* b2    = (const float*)d_in[14];
    float* out = (float*)d_out;

    // ---- workspace carve ----
    int* idg    = (int*)d_ws;                      // NN
    int* cnt    = idg + NN;                        // NN
    int* rowptr = cnt + NN;                        // NN+16
    int* bsum   = rowptr + NN + 16;                // 32
    int* boff   = bsum + 32;                       // 32
    int2* slot  = (int2*)(boff + 32);              // EP (8B-aligned)
    float* asrc1 = (float*)(slot + EP);            // 4*NN
    float* adst1 = asrc1 + 4 * NN;                 // 4*NN
    float* asrc2 = adst1 + 4 * NN;                 // NN
    float* adst2 = asrc2 + NN;                     // NN
    float* vbuf  = adst2 + NN;                     // 64
    unsigned short* ub = (unsigned short*)(((uintptr_t)(vbuf + 64) + 63) & ~(uintptr_t)63);
    unsigned short* x_bf  = ub;                      // NN*128
    unsigned short* W1t   = x_bf + (size_t)NN * 128; // 256*128
    unsigned short* W2t   = W1t + 32768;             // 128*256
    unsigned short* h1_bf = W2t + 32768;             // NN*256
    unsigned short* h2_bf = h1_bf + (size_t)NN * 256;// NN*256
    unsigned short* g2_bf = h2_bf + (size_t)NN * 256;// NN*128

    hipMemsetAsync(idg, 0, (size_t)2 * NN * sizeof(int), stream);

    // prep (v, Wt casts, degree hist, x cast) + CSR build
    k_prep<<<9632, 256, 0, stream>>>(We1, ae1, We2, ae2, vbuf, W1, W1t, W2, W2t,
                                     ei, idg, x, x_bf);
    k_scan1<<<NB, 512, 0, stream>>>(idg, rowptr, bsum);
    k_scan2<<<1, 64, 0, stream>>>(bsum, boff, rowptr);
    k_scan3<<<NB, 512, 0, stream>>>(rowptr, boff);
    k_scatter<<<(EE + 255) / 256, 256, 0, stream>>>(ei, eattr, rowptr, cnt, slot);
    k_selfattr<<<(NN + 255) / 256, 256, 0, stream>>>(rowptr, slot);

    // ---- layer 1 ----  (gemm with fused attn scalars)
    gemm_mfma<128, 4, 4><<<dim3(4, (NN + 127) / 128), 256, 0, stream>>>(
        x_bf, W1t, h1_bf, as1, ad1, asrc1, adst1, NN, 256);
    k_agg1<<<(NN + 3) / 4, 256, 0, stream>>>(rowptr, slot, asrc1, adst1, vbuf,
                                             h1_bf, b1, h2_bf);

    // ---- layer 2 ----
    gemm_mfma<256, 8, 1><<<dim3(1, (NN + 127) / 128), 256, 0, stream>>>(
        h2_bf, W2t, g2_bf, as2, ad2, asrc2, adst2, NN, 128);
    k_agg2<<<(NN + 3) / 4, 256, 0, stream>>>(rowptr, slot, asrc2, adst2, vbuf + 8,
                                             g2_bf, b2, out);
}